// Round 5
// baseline (266.657 us; speedup 1.0000x reference)
//
#include <hip/hip_runtime.h>
#include <hip/hip_bf16.h>
#include <hip/hip_fp16.h>
#include <stdint.h>

// ---------------------------------------------------------------------------
// CLIPAttentionPooling. R14: revert to R12 geometry (128^2 tiles, 256 thr,
// 2 blocks/CU) + two targeted fixes:
//   * s_stats/proj: read order ah,bh,al,bl + MFMA in 3 independent 16-wide
//     passes (hh; cc pass1; cc pass2) -- removes same-acc back-to-back MFMA
//     dependency and lets hh start after half the reads (integer => exact).
//   * av: E operand has reuse=1 -> direct global->VGPR fragment loads (one
//     step of prefetch), LDS staging only for xT (reuse=2) with both-sides
//     XOR chunk swizzle on 128-B rows. Stage LDS 128KB -> 64KB.
// R13 post-mortem: 3-deep/counted-vmcnt at 1 block/CU was a regression;
// monolithic step phases don't overlap regardless of vmcnt depth.
// ---------------------------------------------------------------------------

using half8   = __attribute__((ext_vector_type(8))) _Float16;
using float4v = __attribute__((ext_vector_type(4))) float;
using int4v   = __attribute__((ext_vector_type(4))) int;
using uint2v  = __attribute__((ext_vector_type(2))) unsigned int;

// q/k int16 grid: covers +-6.0, v = QS*(256*hi+lo)
#define QS        (6.0f / 32768.0f)
#define INV_S     (32768.0f / 6.0f)
#define INV_S256  (128.0f / 6.0f)
#define C_HH      (65536.0f * QS * QS)
#define C_X       (256.0f * QS * QS)

// x grid: +-6.0 ; W grid: +-0.25
#define SX        (6.0f / 32768.0f)
#define SW        (0.25f / 32768.0f)
#define P_HH      (65536.0f * SX * SW)
#define P_X       (256.0f * SX * SW)

#define GLOAD_LDS16(gptr, ldsptr)                                              \
  __builtin_amdgcn_global_load_lds(                                            \
      (__attribute__((address_space(1))) void*)(uintptr_t)(gptr),              \
      (__attribute__((address_space(3))) void*)(unsigned)(uintptr_t)(ldsptr),  \
      16, 0, 0)

__device__ __forceinline__ void barrier_raw() {
  asm volatile("" ::: "memory");
  __builtin_amdgcn_s_barrier();
  asm volatile("" ::: "memory");
}

// chunk-level swizzle for the epilogue images (R12-proven).
__device__ __forceinline__ int swz3(int row) {
  return (((row >> 2) & 3) << 1) ^ (row & 3);
}

// ---------------------------------------------------------------------------
// S GEMM + tile softmax stats. Split-i8 16x16x64, 128x128 tile, BK=64.
// R14: R12 structure + read/MFMA reorder for intra-wave overlap.
__global__ __launch_bounds__(256, 2) void gemm_s_stats(
    const int8_t* __restrict__ Ahi, const int8_t* __restrict__ Alo,
    const int8_t* __restrict__ Bhi, const int8_t* __restrict__ Blo,
    _Float16* __restrict__ E, float2* __restrict__ stats)
{
  __shared__ __align__(16) int8_t smem[65536];
  int8_t* sAh = smem;            // [2][8192]
  int8_t* sAl = smem + 16384;    // [2][8192]
  int8_t* sBh = smem + 32768;    // [2][8192]
  int8_t* sBl = smem + 49152;    // [2][8192]

  const int tid  = threadIdx.x;
  const int wave = tid >> 6;
  const int lane = tid & 63;
  const int quad = lane >> 4;
  const int t16  = lane & 15;
  const int wm   = wave & 1;
  const int wn   = wave >> 1;
  const int row0 = blockIdx.y * 128;
  const int col0 = blockIdx.x * 128;

  const int seg  = lane & 3;   // 16B chunk within 64B row
  const int rsub = lane >> 2;  // row within 16-row stripe

  const int offA0 = (row0 + wave * 16 + rsub) * 2048 + seg * 16;
  const int offA1 = offA0 + 64 * 2048;
  const int offB0 = (col0 + wave * 16 + rsub) * 2048 + seg * 16;
  const int offB1 = offB0 + 64 * 2048;
  const int ldsT0 = (wave * 16) * 64;
  const int ldsT1 = (64 + wave * 16) * 64;

  int4v hh[4][4], cc[4][4];
#pragma unroll
  for (int i = 0; i < 4; ++i)
#pragma unroll
    for (int j = 0; j < 4; ++j) {
      hh[i][j] = (int4v){0, 0, 0, 0};
      cc[i][j] = (int4v){0, 0, 0, 0};
    }

  auto stage_k = [&](int ks, int b) {
    const int k0 = ks * 64;
    GLOAD_LDS16(Ahi + offA0 + k0, sAh + b * 8192 + ldsT0);
    GLOAD_LDS16(Ahi + offA1 + k0, sAh + b * 8192 + ldsT1);
    GLOAD_LDS16(Alo + offA0 + k0, sAl + b * 8192 + ldsT0);
    GLOAD_LDS16(Alo + offA1 + k0, sAl + b * 8192 + ldsT1);
    GLOAD_LDS16(Bhi + offB0 + k0, sBh + b * 8192 + ldsT0);
    GLOAD_LDS16(Bhi + offB1 + k0, sBh + b * 8192 + ldsT1);
    GLOAD_LDS16(Blo + offB0 + k0, sBl + b * 8192 + ldsT0);
    GLOAD_LDS16(Blo + offB1 + k0, sBl + b * 8192 + ldsT1);
  };

  stage_k(0, 0);
  asm volatile("s_waitcnt vmcnt(0)" ::: "memory");
  barrier_raw();

  int buf = 0;
  for (int ks = 0; ks < 16; ++ks) {
    if (ks < 15) stage_k(ks + 1, buf ^ 1);

    // reads ordered so the hh MFMA cluster can start after ah+bh arrive;
    // al/bl reads complete under the hh MFMAs (fine-grained lgkmcnt).
    int4v ah[4], al[4], bh[4], bl[4];
#pragma unroll
    for (int i = 0; i < 4; ++i) {
      const int ao = buf * 8192 + (wm * 64 + i * 16 + t16) * 64 + quad * 16;
      ah[i] = *(const int4v*)(sAh + ao);
    }
#pragma unroll
    for (int j = 0; j < 4; ++j) {
      const int bo = buf * 8192 + (wn * 64 + j * 16 + t16) * 64 + quad * 16;
      bh[j] = *(const int4v*)(sBh + bo);
    }
#pragma unroll
    for (int i = 0; i < 4; ++i) {
      const int ao = buf * 8192 + (wm * 64 + i * 16 + t16) * 64 + quad * 16;
      al[i] = *(const int4v*)(sAl + ao);
    }
#pragma unroll
    for (int j = 0; j < 4; ++j) {
      const int bo = buf * 8192 + (wn * 64 + j * 16 + t16) * 64 + quad * 16;
      bl[j] = *(const int4v*)(sBl + bo);
    }

    // three independent 16-wide passes: no same-accumulator adjacency.
    __builtin_amdgcn_s_setprio(1);
#pragma unroll
    for (int i = 0; i < 4; ++i)
#pragma unroll
      for (int j = 0; j < 4; ++j)
        hh[i][j] = __builtin_amdgcn_mfma_i32_16x16x64_i8(ah[i], bh[j], hh[i][j], 0, 0, 0);
#pragma unroll
    for (int i = 0; i < 4; ++i)
#pragma unroll
      for (int j = 0; j < 4; ++j)
        cc[i][j] = __builtin_amdgcn_mfma_i32_16x16x64_i8(ah[i], bl[j], cc[i][j], 0, 0, 0);
#pragma unroll
    for (int i = 0; i < 4; ++i)
#pragma unroll
      for (int j = 0; j < 4; ++j)
        cc[i][j] = __builtin_amdgcn_mfma_i32_16x16x64_i8(al[i], bh[j], cc[i][j], 0, 0, 0);
    __builtin_amdgcn_s_setprio(0);

    if (ks < 15) asm volatile("s_waitcnt vmcnt(0)" ::: "memory");
    barrier_raw();
    buf ^= 1;
  }

  // ---- epilogue: tile-local softmax stats + LDS-image E store -------------
  float* red = (float*)smem;  // buf-0 region; final reads were from buf 1

  float vv[4][4][4];
  float rmax[4][4];
#pragma unroll
  for (int i = 0; i < 4; ++i)
#pragma unroll
    for (int r = 0; r < 4; ++r) {
      float mx = -3.0e38f;
#pragma unroll
      for (int j = 0; j < 4; ++j) {
        float v = C_HH * (float)hh[i][j][r] + C_X * (float)cc[i][j][r];
        vv[i][j][r] = v;
        mx = fmaxf(mx, v);
      }
      mx = fmaxf(mx, __shfl_xor(mx, 1));
      mx = fmaxf(mx, __shfl_xor(mx, 2));
      mx = fmaxf(mx, __shfl_xor(mx, 4));
      mx = fmaxf(mx, __shfl_xor(mx, 8));
      rmax[i][r] = mx;
    }
  if (t16 == 0) {
#pragma unroll
    for (int i = 0; i < 4; ++i)
#pragma unroll
      for (int r = 0; r < 4; ++r)
        red[wn * 128 + wm * 64 + i * 16 + quad * 4 + r] = rmax[i][r];
  }
  __syncthreads();

  float mrow[4][4];
#pragma unroll
  for (int i = 0; i < 4; ++i)
#pragma unroll
    for (int r = 0; r < 4; ++r) {
      const int row = wm * 64 + i * 16 + quad * 4 + r;
      mrow[i][r] = fmaxf(red[row], red[128 + row]);
    }

  float rsum[4][4];
#pragma unroll
  for (int i = 0; i < 4; ++i)
#pragma unroll
    for (int r = 0; r < 4; ++r) {
      float s = 0.f;
#pragma unroll
      for (int j = 0; j < 4; ++j) {
        float e = __expf(vv[i][j][r] - mrow[i][r]);
        vv[i][j][r] = e;
        s += e;
      }
      s += __shfl_xor(s, 1);
      s += __shfl_xor(s, 2);
      s += __shfl_xor(s, 4);
      s += __shfl_xor(s, 8);
      rsum[i][r] = s;
    }
  if (t16 == 0) {
#pragma unroll
    for (int i = 0; i < 4; ++i)
#pragma unroll
      for (int r = 0; r < 4; ++r)
        red[256 + wn * 128 + wm * 64 + i * 16 + quad * 4 + r] = rsum[i][r];
  }

  // E fragments -> swizzled u16 image (overlays sBh/sBl: dead after K loop)
  uint16_t* img = (uint16_t*)(smem + 32768);  // [128][128] u16 = 32 KB
#pragma unroll
  for (int i = 0; i < 4; ++i)
#pragma unroll
    for (int j = 0; j < 4; ++j)
#pragma unroll
      for (int r = 0; r < 4; ++r) {
        const int row  = wm * 64 + i * 16 + quad * 4 + r;
        const int col  = wn * 64 + j * 16 + t16;
        const int colS = col ^ (((quad << 1) ^ r) << 3);
        _Float16 h = (_Float16)vv[i][j][r];
        img[row * 128 + colS] = *(const uint16_t*)&h;
      }
  __syncthreads();  // covers red-sum writes AND img writes

  // coalesced E store: 8 x b128 per thread
#pragma unroll
  for (int it = 0; it < 8; ++it) {
    const int row    = wave * 32 + it * 4 + quad;
    const int chunkS = t16 ^ swz3(row);
    int4v v = *(const int4v*)&img[row * 128 + chunkS * 8];
    *(int4v*)&E[(size_t)(row0 + row) * 4096 + col0 + t16 * 8] = v;
  }

  if (wn == 0 && t16 == 0) {
#pragma unroll
    for (int i = 0; i < 4; ++i)
#pragma unroll
      for (int r = 0; r < 4; ++r) {
        const int row = wm * 64 + i * 16 + quad * 4 + r;
        const float l = red[256 + row] + red[256 + 128 + row];
        stats[(size_t)(row0 + row) * 32 + blockIdx.x] =
            make_float2(mrow[i][r], l);
      }
  }
}

// ---------------------------------------------------------------------------
// proj: qk = x Wqk^T + bias. R12 structure + read/MFMA reorder.
__global__ __launch_bounds__(256, 2) void gemm_proj_i8(
    const int8_t* __restrict__ Ahi, const int8_t* __restrict__ Alo,
    const int8_t* __restrict__ Bhi, const int8_t* __restrict__ Blo,
    const float* __restrict__ biasQ, const float* __restrict__ biasK,
    int8_t* __restrict__ Ch, int8_t* __restrict__ Cl)
{
  __shared__ __align__(16) int8_t smem[65536];
  int8_t* sAh = smem;
  int8_t* sAl = smem + 16384;
  int8_t* sBh = smem + 32768;
  int8_t* sBl = smem + 49152;

  const int tid  = threadIdx.x;
  const int wave = tid >> 6;
  const int lane = tid & 63;
  const int quad = lane >> 4;
  const int t16  = lane & 15;
  const int wm   = wave & 1;
  const int wn   = wave >> 1;
  const int row0 = blockIdx.y * 128;
  const int col0 = blockIdx.x * 128;

  const int seg  = lane & 3;
  const int rsub = lane >> 2;

  const int offA0 = (row0 + wave * 16 + rsub) * 1024 + seg * 16;
  const int offA1 = offA0 + 64 * 1024;
  const int offB0 = (col0 + wave * 16 + rsub) * 1024 + seg * 16;
  const int offB1 = offB0 + 64 * 1024;
  const int ldsT0 = (wave * 16) * 64;
  const int ldsT1 = (64 + wave * 16) * 64;

  int4v hh[4][4], cc[4][4];
#pragma unroll
  for (int i = 0; i < 4; ++i)
#pragma unroll
    for (int j = 0; j < 4; ++j) {
      hh[i][j] = (int4v){0, 0, 0, 0};
      cc[i][j] = (int4v){0, 0, 0, 0};
    }

  auto stage_k = [&](int ks, int b) {
    const int k0 = ks * 64;
    GLOAD_LDS16(Ahi + offA0 + k0, sAh + b * 8192 + ldsT0);
    GLOAD_LDS16(Ahi + offA1 + k0, sAh + b * 8192 + ldsT1);
    GLOAD_LDS16(Alo + offA0 + k0, sAl + b * 8192 + ldsT0);
    GLOAD_LDS16(Alo + offA1 + k0, sAl + b * 8192 + ldsT1);
    GLOAD_LDS16(Bhi + offB0 + k0, sBh + b * 8192 + ldsT0);
    GLOAD_LDS16(Bhi + offB1 + k0, sBh + b * 8192 + ldsT1);
    GLOAD_LDS16(Blo + offB0 + k0, sBl + b * 8192 + ldsT0);
    GLOAD_LDS16(Blo + offB1 + k0, sBl + b * 8192 + ldsT1);
  };

  stage_k(0, 0);
  asm volatile("s_waitcnt vmcnt(0)" ::: "memory");
  barrier_raw();

  int buf = 0;
  for (int ks = 0; ks < 16; ++ks) {
    if (ks < 15) stage_k(ks + 1, buf ^ 1);

    int4v ah[4], al[4], bh[4], bl[4];
#pragma unroll
    for (int i = 0; i < 4; ++i) {
      const int ao = buf * 8192 + (wm * 64 + i * 16 + t16) * 64 + quad * 16;
      ah[i] = *(const int4v*)(sAh + ao);
    }
#pragma unroll
    for (int j = 0; j < 4; ++j) {
      const int bo = buf * 8192 + (wn * 64 + j * 16 + t16) * 64 + quad * 16;
      bh[j] = *(const int4v*)(sBh + bo);
    }
#pragma unroll
    for (int i = 0; i < 4; ++i) {
      const int ao = buf * 8192 + (wm * 64 + i * 16 + t16) * 64 + quad * 16;
      al[i] = *(const int4v*)(sAl + ao);
    }
#pragma unroll
    for (int j = 0; j < 4; ++j) {
      const int bo = buf * 8192 + (wn * 64 + j * 16 + t16) * 64 + quad * 16;
      bl[j] = *(const int4v*)(sBl + bo);
    }

    __builtin_amdgcn_s_setprio(1);
#pragma unroll
    for (int i = 0; i < 4; ++i)
#pragma unroll
      for (int j = 0; j < 4; ++j)
        hh[i][j] = __builtin_amdgcn_mfma_i32_16x16x64_i8(ah[i], bh[j], hh[i][j], 0, 0, 0);
#pragma unroll
    for (int i = 0; i < 4; ++i)
#pragma unroll
      for (int j = 0; j < 4; ++j)
        cc[i][j] = __builtin_amdgcn_mfma_i32_16x16x64_i8(ah[i], bl[j], cc[i][j], 0, 0, 0);
#pragma unroll
    for (int i = 0; i < 4; ++i)
#pragma unroll
      for (int j = 0; j < 4; ++j)
        cc[i][j] = __builtin_amdgcn_mfma_i32_16x16x64_i8(al[i], bh[j], cc[i][j], 0, 0, 0);
    __builtin_amdgcn_s_setprio(0);

    if (ks < 15) asm volatile("s_waitcnt vmcnt(0)" ::: "memory");
    barrier_raw();
    buf ^= 1;
  }

  // ---- epilogue: quant -> packed u16 image -> coalesced plane stores ------
  uint16_t* img = (uint16_t*)(smem + 32768);  // [128][128] u16
#pragma unroll
  for (int i = 0; i < 4; ++i) {
#pragma unroll
    for (int j = 0; j < 4; ++j) {
      const int ccol = col0 + wn * 64 + j * 16 + t16;
      const float* bp = (ccol < 1024) ? biasQ : (biasK - 1024);
#pragma unroll
      for (int r = 0; r < 4; ++r) {
        float v = P_HH * (float)hh[i][j][r] + P_X * (float)cc[i][j][r] + bp[ccol];
        int hi = (int)lrintf(v * INV_S256);
        hi = hi > 127 ? 127 : (hi < -127 ? -127 : hi);
        int lo = (int)lrintf(v * INV_S - 256.0f * (float)hi);
        lo = lo > 127 ? 127 : (lo < -127 ? -127 : lo);
        const int row  = wm * 64 + i * 16 + quad * 4 + r;
        const int col  = wn * 64 + j * 16 + t16;
        const int colS = col ^ (((quad << 1) ^ r) << 3);
        img[row * 128 + colS] = (uint16_t)((hi & 0xff) | ((lo & 0xff) << 8));
      }
    }
  }
  __syncthreads();

#pragma unroll
  for (int it = 0; it < 8; ++it) {
    const int row    = wave * 32 + it * 4 + quad;
    const int chunkS = t16 ^ swz3(row);
    int4v p = *(const int4v*)&img[row * 128 + chunkS * 8];
    const unsigned w0 = (unsigned)p[0], w1 = (unsigned)p[1];
    const unsigned w2 = (unsigned)p[2], w3 = (unsigned)p[3];
    uint2v hw, lw;
    hw[0] = (w0 & 0xffu) | (((w0 >> 16) & 0xffu) << 8) |
            ((w1 & 0xffu) << 16) | (((w1 >> 16) & 0xffu) << 24);
    hw[1] = (w2 & 0xffu) | (((w2 >> 16) & 0xffu) << 8) |
            ((w3 & 0xffu) << 16) | (((w3 >> 16) & 0xffu) << 24);
    lw[0] = ((w0 >> 8) & 0xffu) | (((w0 >> 24) & 0xffu) << 8) |
            (((w1 >> 8) & 0xffu) << 16) | ((w1 >> 24) << 24);
    lw[1] = ((w2 >> 8) & 0xffu) | (((w2 >> 24) & 0xffu) << 8) |
            (((w3 >> 8) & 0xffu) << 16) | ((w3 >> 24) << 24);
    const size_t go = (size_t)(row0 + row) * 2048 + col0 + t16 * 8;
    *(uint2v*)&Ch[go] = hw;
    *(uint2v*)&Cl[go] = lw;
  }
}

// ---------------------------------------------------------------------------
// AV: out = sum_t beta_t (E_t x). 512 thr, in-block split-K=2 (z = wave>>2).
// R14: E (reuse=1) loaded global->VGPR directly with 1-step prefetch; only
// xT staged in LDS (2 bufs, XOR chunk swizzle on 128-B rows, both sides).
// 32 steps of 64 cols; one vmcnt(0)+barrier per step.
__global__ __launch_bounds__(512) void gemm_av(
    const uint16_t* __restrict__ E, const uint16_t* __restrict__ B,
    const float2* __restrict__ stats, float* __restrict__ out)
{
  __shared__ __align__(16) uint16_t stg[2][2][8192];  // [buf][z][128x64] 64KB
  __shared__ float betaS[128 * 33];

  const int L      = blockIdx.x;        // 0..255
  const int xcd    = L & 7;
  const int rest   = L >> 3;            // 0..31
  const int colb   = rest & 7;          // 0..7
  const int bandHi = rest >> 3;         // 0..3
  const int band   = xcd + 8 * bandHi;  // 0..31
  const int row0   = band * 128;
  const int col0   = colb * 128;

  const int tid  = threadIdx.x;
  const int wave = tid >> 6;
  const int z    = wave >> 2;           // 0..1 K-half
  const int gw   = wave & 3;            // group-local wave
  const int lane = tid & 63;
  const int quad = lane >> 4;
  const int t16  = lane & 15;
  const int wm   = gw & 1;
  const int wn   = gw >> 1;

  const int r8 = lane >> 3;             // staging row within 8-row stripe
  const int c8 = lane & 7;              // staging 16B chunk within 128B row

  // E fragment offsets (halves): row0 + wm*64+i*16+t16 rows, z half of K.
  int offE[2][4];
#pragma unroll
  for (int ks = 0; ks < 2; ++ks)
#pragma unroll
    for (int i = 0; i < 4; ++i)
      offE[ks][i] = (row0 + wm * 64 + i * 16 + t16) * 4096 + z * 2048 +
                    ks * 32 + quad * 8;

  // xT stage offsets (bytes): 4 passes of 32 rows; source chunk pre-swizzled.
  int offB[4];
#pragma unroll
  for (int p = 0; p < 4; ++p)
    offB[p] = (col0 + p * 32 + gw * 8 + r8) * 8192 + z * 4096 + ((c8 ^ r8) * 16);

  auto stage_B = [&](int s, int b) {
    const int k0b = s * 128;  // bytes
    int8_t* dst = (int8_t*)&stg[b][z][0];
#pragma unroll
    for (int p = 0; p < 4; ++p)
      GLOAD_LDS16((const int8_t*)B + offB[p] + k0b, dst + (p * 32 + gw * 8) * 128);
  };

  half8 afA[2][4], afB[2][4];
  auto load_E = [&](int s, half8 (&dstf)[2][4]) {
    const int k0h = s * 64;
#pragma unroll
    for (int ks = 0; ks < 2; ++ks)
#pragma unroll
      for (int i = 0; i < 4; ++i)
        dstf[ks][i] = *(const half8*)&E[offE[ks][i] + k0h];
  };

  stage_B(0, 0);
  load_E(0, afA);

  // ---- beta prologue: threads 0..127, one row each ------------------------
  if (tid < 128) {
    const int row = row0 + tid;
    float2 st[32];
    float m = -3.0e38f;
#pragma unroll
    for (int t = 0; t < 32; ++t) {
      st[t] = stats[(size_t)row * 32 + t];
      m = fmaxf(m, st[t].x);
    }
    float l = 0.f;
#pragma unroll
    for (int t = 0; t < 32; ++t) l += st[t].y * __expf(st[t].x - m);
    const float inv = 1.0f / l;
#pragma unroll
    for (int t = 0; t < 32; ++t)
      betaS[tid * 33 + t] = __expf(st[t].x - m) * inv;
  }
  asm volatile("s_waitcnt vmcnt(0)" ::: "memory");
  __syncthreads();

  float4v acc[4][4];
#pragma unroll
  for (int i = 0; i < 4; ++i)
#pragma unroll
    for (int j = 0; j < 4; ++j)
      acc[i][j] = (float4v){0.f, 0.f, 0.f, 0.f};

  // one step: consume (cur, stg[b]); prefetch (nxt, stg[b^1]) for s+1.
  auto step = [&](int s, int b, half8 (&cur)[2][4], half8 (&nxt)[2][4]) {
    if (s < 31) {
      load_E(s + 1, nxt);      // global->VGPR, drains at step-end vmcnt
      stage_B(s + 1, b ^ 1);   // global->LDS
    }

    const int t = z * 16 + (s >> 1);
    _Float16 bb[4];
#pragma unroll
    for (int i = 0; i < 4; ++i)
      bb[i] = (_Float16)betaS[(wm * 64 + i * 16 + t16) * 33 + t];

    const uint16_t* sB = &stg[b][z][0];
    half8 bf[2][4];
#pragma unroll
    for (int ks = 0; ks < 2; ++ks)
#pragma unroll
      for (int j = 0; j < 4; ++j) {
        const int row = wn * 64 + j * 16 + t16;
        const int ch  = (ks * 4 + quad) ^ (t16 & 7);
        bf[ks][j] = *(const half8*)&sB[row * 64 + ch * 8];
      }

    __builtin_amdgcn_s_setprio(1);
#pragma unroll
    for (int ks = 0; ks < 2; ++ks) {
      half8 afs[4];
#pragma unroll
      for (int i = 0; i < 4; ++i) {
        half8 bs;
#pragma unroll
        for (int c = 0; c < 8; ++c) bs[c] = bb[i];
        afs[i] = cur[ks][i] * bs;
      }
#pragma unroll
      for (int i = 0; i < 4; ++i)
#pragma unroll
        for (int j = 0; j < 4; ++j)
          acc[i][j] = __builtin_amdgcn_mfma_f32_16x16x32_f16(afs[i], bf[ks][j], acc[i][j], 0, 0, 0);
    }
    __builtin_amdgcn_s_setprio(0);

    if (s < 31) asm volatile("s_waitcnt vmcnt(0)" ::: "memory");
    barrier_raw();
  };

  for (int s2 = 0; s2 < 32; s2 += 2) {
    step(s2,     0, afA, afB);
    step(s2 + 1, 1, afB, afA);
  }

  // ---- combine group1 -> group0 via LDS (two 16 KB halves) ----------------
  float* xfer = (float*)stg;  // 32 KB region, staging dead
#pragma unroll
  for (int h = 0; h < 2; ++h) {
    if (z == 1) {
#pragma unroll
      for (int i = 2 * h; i < 2 * h + 2; ++i)
#pragma unroll
        for (int j = 0; j < 4; ++j)
#pragma unroll
          for (int r = 0; r < 4; ++r) {
            const int e = (i - 2 * h) * 16 + j * 4 + r;
            xfer[e * 256 + gw * 64 + lane] = acc[i][j][r];
          }
    }
    __syncthreads();
    if (z == 0) {
#pragma unroll
      for (int i = 2 * h; i < 2 * h + 2; ++i)
#pragma unroll
        for (int j = 0; j < 4; ++j)
#pragma unroll
          for (int r = 0; r < 4; ++r) {
            const int e = (i - 2 * h) * 16 + j * 4 + r;
            acc[i][j][r] += xfer[e * 256 + gw * 64 + lane];
          }
    }
    __syncthreads();
  }

  // ---- fp32 image store: z=0 writes image, ALL 512 threads store ----------
  float* img = (float*)stg;  // [128][128] f32 = 64 KB (whole stage region)
  if (z == 0) {
#pragma unroll
    for (int i = 0; i < 4; ++i)
#pragma unroll
      for (int j = 0; j < 4; ++j)
#pragma unroll
        for (int r = 0; r < 4; ++r) {
          const int row  = wm * 64 + i * 16 + quad * 4 + r;
          const int col  = wn * 64 + j * 16 + t16;
          const int colS = col ^ (((quad << 1) ^ r) << 2);
          img[row * 128 + colS] = acc[i][j][r];
        }
  }
  __syncthreads();

#pragma unroll
  for (int it = 0; it < 8; ++it) {
    const int row    = wave * 16 + (lane >> 2);
    const int chunk  = (lane & 3) * 8 + it;          // 32 chunks of 4 floats
    const int chunkS = chunk ^ swz3(row);
    float4v v = *(const float4v*)&img[row * 128 + chunkS * 4];
    *(float4v*)&out[(size_t)(row0 + row) * 1024 + col0 + chunk * 4] = v;
  }
}

// ---------------------------------------------------------------------------
// Fused quant + transpose-cast (unchanged).
__global__ __launch_bounds__(256) void quantT(
    const float* __restrict__ x, const float* __restrict__ Wq,
    const float* __restrict__ Wk,
    int8_t* __restrict__ xhi, int8_t* __restrict__ xlo,
    int8_t* __restrict__ whi, int8_t* __restrict__ wlo,
    uint16_t* __restrict__ xT)
{
  if (blockIdx.x < 6144) {
    int i = blockIdx.x * 256 + threadIdx.x;  // 0..1572863
    const float* src; int8_t* dh; int8_t* dl; int idx; float s256, s;
    if (i < 1048576)      { src = x;  idx = i;           dh = xhi; dl = xlo;
                            s256 = INV_S256; s = INV_S; }
    else if (i < 1310720) { src = Wq; idx = i - 1048576; dh = whi; dl = wlo;
                            s256 = 512.0f; s = 131072.0f; }
    else                  { src = Wk; idx = i - 1310720; dh = whi + 1048576;
                            dl = wlo + 1048576; s256 = 512.0f; s = 131072.0f; }
    float4 v = ((const float4*)src)[idx];
    float vv[4] = {v.x, v.y, v.z, v.w};
    int hp = 0, lp = 0;
#pragma unroll
    for (int c = 0; c < 4; ++c) {
      int h = (int)lrintf(vv[c] * s256);
      h = h > 127 ? 127 : (h < -127 ? -127 : h);
      int l = (int)lrintf(vv[c] * s - 256.0f * (float)h);
      l = l > 127 ? 127 : (l < -127 ? -127 : l);
      hp |= (h & 0xff) << (8 * c);
      lp |= (l & 0xff) << (8 * c);
    }
    ((int*)dh)[idx] = hp;
    ((int*)dl)[idx] = lp;
  } else {
    __shared__ float tile[32][33];
    const int tb = blockIdx.x - 6144;   // 0..4095
    const int bx = tb & 31;             // D/32
    const int by = tb >> 5;             // N/32
    const int tx = threadIdx.x & 31;
    const int ty = threadIdx.x >> 5;    // 0..7
#pragma unroll
    for (int p = 0; p < 4; ++p) {
      const int row = by * 32 + ty + p * 8;
      tile[ty + p * 8][tx] = x[(size_t)row * 1024 + bx * 32 + tx];
    }
    __syncthreads();
#pragma unroll
    for (int p = 0; p < 4; ++p) {
      const int oc = ty + p * 8;  // local col in x == local row in xT
      __half hv = __float2half_rn(tile[tx][oc]);
      xT[(size_t)(bx * 32 + oc) * 4096 + by * 32 + tx] = *(uint16_t*)&hv;
    }
  }
}

extern "C" void kernel_launch(void* const* d_in, const int* in_sizes, int n_in,
                              void* d_out, int out_size, void* d_ws, size_t ws_size,
                              hipStream_t stream) {
  const int N = 4096, D = 1024;
  const float* x  = (const float*)d_in[0];
  const float* Wq = (const float*)d_in[1];
  const float* bq = (const float*)d_in[2];
  const float* Wk = (const float*)d_in[3];
  const float* bk = (const float*)d_in[4];
  float* out = (float*)d_out;

  // workspace layout (MiB offsets)
  char* w = (char*)d_ws;
  const size_t MiB = 1024 * 1024;
  int8_t*    xq_hi  = (int8_t*)   (w + 0  * MiB);  // [N x D]
  int8_t*    xq_lo  = (int8_t*)   (w + 4  * MiB);
  int8_t*    Wqk_hi = (int8_t*)   (w + 8  * MiB);  // [2048 x D]
  int8_t*    Wqk_lo = (int8_t*)   (w + 10 * MiB);
  int8_t*    qk_hi  = (int8_t*)   (w + 12 * MiB);  // [N x 2048]
  int8_t*    qk_lo  = (int8_t*)   (w + 20 * MiB);
  _Float16*  E      = (_Float16*) (w + 36 * MiB);  // [N x N] fp16, 32 MiB
  float2*    stats  = (float2*)   (w + 68 * MiB);  // [N x 32] (m,l), 1 MiB
  uint16_t*  xTh    = (uint16_t*) (w + 72 * MiB);  // [D x N] fp16
  // total 80 MiB

  // 1) fused quantization + transpose-cast  (6144 + 4096 blocks)
  quantT<<<10240, 256, 0, stream>>>(x, Wq, Wk, xq_hi, xq_lo, Wqk_hi, Wqk_lo,
                                    xTh);

  // 2) fused qk projection: i8 16x16x64, 3-MFMA, bias+quant epilogue
  gemm_proj_i8<<<dim3(2048 / 128, N / 128), 256, 0, stream>>>(
      xq_hi, xq_lo, Wqk_hi, Wqk_lo, bq, bk, qk_hi, qk_lo);

  // 3) S = q k^T + tile softmax stats -> E fp16, stats (m_t, l_t)
  gemm_s_stats<<<dim3(N / 128, N / 128), 256, 0, stream>>>(
      qk_hi, qk_lo, qk_hi + 1024, qk_lo + 1024, E, stats);

  // 4) out = sum_t beta_t (E_t x): beta prologue + in-block split-K=2
  gemm_av<<<256, 512, 0, stream>>>((const uint16_t*)E, xTh, stats, out);

  (void)in_sizes; (void)n_in; (void)out_size; (void)ws_size;
}

// Round 6
// 215.201 us; speedup vs baseline: 1.2391x; 1.2391x over previous
//
#include <hip/hip_runtime.h>
#include <hip/hip_bf16.h>
#include <hip/hip_fp16.h>
#include <stdint.h>

// ---------------------------------------------------------------------------
// CLIPAttentionPooling. R15: 3-phase K-step (m201-style) for s_stats/proj;
// av reverted to the R12 implementation (R14's global->VGPR E loads were
// 16-line-per-instruction uncoalesced: 96us).
// Phase structure per K-step (2 LDS bufs, loads span 3 barriers, FIFO vmcnt):
//   P1: vmcnt(4); bar; stage Ahi/Bhi(s+1); read ah,bh; 16x hh-MFMA
//   P2: vmcnt(6); bar; stage Blo(s+1);     read bl;    16x cc-MFMA (ah*bl)
//   P3: vmcnt(6); bar; stage Alo(s+1);     read al;    16x cc-MFMA (al*bh)
// (tail: 4/2/0). Stages issued AFTER the barrier => no read/overwrite race.
// ---------------------------------------------------------------------------

using half8   = __attribute__((ext_vector_type(8))) _Float16;
using float4v = __attribute__((ext_vector_type(4))) float;
using int4v   = __attribute__((ext_vector_type(4))) int;
using uint2v  = __attribute__((ext_vector_type(2))) unsigned int;

// q/k int16 grid: covers +-6.0, v = QS*(256*hi+lo)
#define QS        (6.0f / 32768.0f)
#define INV_S     (32768.0f / 6.0f)
#define INV_S256  (128.0f / 6.0f)
#define C_HH      (65536.0f * QS * QS)
#define C_X       (256.0f * QS * QS)

// x grid: +-6.0 ; W grid: +-0.25
#define SX        (6.0f / 32768.0f)
#define SW        (0.25f / 32768.0f)
#define P_HH      (65536.0f * SX * SW)
#define P_X       (256.0f * SX * SW)

#define GLOAD_LDS16(gptr, ldsptr)                                              \
  __builtin_amdgcn_global_load_lds(                                            \
      (__attribute__((address_space(1))) void*)(uintptr_t)(gptr),              \
      (__attribute__((address_space(3))) void*)(unsigned)(uintptr_t)(ldsptr),  \
      16, 0, 0)

__device__ __forceinline__ void barrier_raw() {
  asm volatile("" ::: "memory");
  __builtin_amdgcn_s_barrier();
  asm volatile("" ::: "memory");
}

// chunk-level swizzle for the epilogue images (R12-proven).
__device__ __forceinline__ int swz3(int row) {
  return (((row >> 2) & 3) << 1) ^ (row & 3);
}

// ---------------------------------------------------------------------------
// S GEMM + tile softmax stats. Split-i8 16x16x64, 128x128 tile, BK=64.
// R15: 3-phase K-step with cross-barrier loads (see header).
__global__ __launch_bounds__(256, 2) void gemm_s_stats(
    const int8_t* __restrict__ Ahi, const int8_t* __restrict__ Alo,
    const int8_t* __restrict__ Bhi, const int8_t* __restrict__ Blo,
    _Float16* __restrict__ E, float2* __restrict__ stats)
{
  __shared__ __align__(16) int8_t smem[65536];
  int8_t* sAh = smem;            // [2][8192]
  int8_t* sAl = smem + 16384;    // [2][8192]
  int8_t* sBh = smem + 32768;    // [2][8192]
  int8_t* sBl = smem + 49152;    // [2][8192]

  const int tid  = threadIdx.x;
  const int wave = tid >> 6;
  const int lane = tid & 63;
  const int quad = lane >> 4;
  const int t16  = lane & 15;
  const int wm   = wave & 1;
  const int wn   = wave >> 1;
  const int row0 = blockIdx.y * 128;
  const int col0 = blockIdx.x * 128;

  const int seg  = lane & 3;   // 16B chunk within 64B row
  const int rsub = lane >> 2;  // row within 16-row stripe

  const int offA0 = (row0 + wave * 16 + rsub) * 2048 + seg * 16;
  const int offA1 = offA0 + 64 * 2048;
  const int offB0 = (col0 + wave * 16 + rsub) * 2048 + seg * 16;
  const int offB1 = offB0 + 64 * 2048;
  const int ldsT0 = (wave * 16) * 64;
  const int ldsT1 = (64 + wave * 16) * 64;

  int4v hh[4][4], cc[4][4];
#pragma unroll
  for (int i = 0; i < 4; ++i)
#pragma unroll
    for (int j = 0; j < 4; ++j) {
      hh[i][j] = (int4v){0, 0, 0, 0};
      cc[i][j] = (int4v){0, 0, 0, 0};
    }

  // staging split to match phase consumption order (FIFO vmcnt counting)
  auto stage_AhBh = [&](int ks, int b) {
    const int k0 = ks * 64;
    GLOAD_LDS16(Ahi + offA0 + k0, sAh + b * 8192 + ldsT0);
    GLOAD_LDS16(Ahi + offA1 + k0, sAh + b * 8192 + ldsT1);
    GLOAD_LDS16(Bhi + offB0 + k0, sBh + b * 8192 + ldsT0);
    GLOAD_LDS16(Bhi + offB1 + k0, sBh + b * 8192 + ldsT1);
  };
  auto stage_Bl = [&](int ks, int b) {
    const int k0 = ks * 64;
    GLOAD_LDS16(Blo + offB0 + k0, sBl + b * 8192 + ldsT0);
    GLOAD_LDS16(Blo + offB1 + k0, sBl + b * 8192 + ldsT1);
  };
  auto stage_Al = [&](int ks, int b) {
    const int k0 = ks * 64;
    GLOAD_LDS16(Alo + offA0 + k0, sAl + b * 8192 + ldsT0);
    GLOAD_LDS16(Alo + offA1 + k0, sAl + b * 8192 + ldsT1);
  };

  // prologue: step 0 staged in consumption order (8 loads outstanding)
  stage_AhBh(0, 0);
  stage_Bl(0, 0);
  stage_Al(0, 0);

  int buf = 0;
  for (int ks = 0; ks < 16; ++ks) {
    // ---- P1: hh pass ----
    asm volatile("s_waitcnt vmcnt(4)" ::: "memory");   // Ahi/Bhi(ks) landed
    barrier_raw();
    if (ks < 15) stage_AhBh(ks + 1, buf ^ 1);

    int4v ah[4], bh[4];
#pragma unroll
    for (int i = 0; i < 4; ++i)
      ah[i] = *(const int4v*)(sAh + buf * 8192 +
                              (wm * 64 + i * 16 + t16) * 64 + quad * 16);
#pragma unroll
    for (int j = 0; j < 4; ++j)
      bh[j] = *(const int4v*)(sBh + buf * 8192 +
                              (wn * 64 + j * 16 + t16) * 64 + quad * 16);

    __builtin_amdgcn_s_setprio(1);
#pragma unroll
    for (int i = 0; i < 4; ++i)
#pragma unroll
      for (int j = 0; j < 4; ++j)
        hh[i][j] = __builtin_amdgcn_mfma_i32_16x16x64_i8(ah[i], bh[j], hh[i][j], 0, 0, 0);
    __builtin_amdgcn_s_setprio(0);

    // ---- P2: cc pass 1 (ah * bl) ----
    if (ks < 15) asm volatile("s_waitcnt vmcnt(6)" ::: "memory");
    else         asm volatile("s_waitcnt vmcnt(2)" ::: "memory");
    barrier_raw();
    if (ks < 15) stage_Bl(ks + 1, buf ^ 1);

    int4v bl[4];
#pragma unroll
    for (int j = 0; j < 4; ++j)
      bl[j] = *(const int4v*)(sBl + buf * 8192 +
                              (wn * 64 + j * 16 + t16) * 64 + quad * 16);

    __builtin_amdgcn_s_setprio(1);
#pragma unroll
    for (int i = 0; i < 4; ++i)
#pragma unroll
      for (int j = 0; j < 4; ++j)
        cc[i][j] = __builtin_amdgcn_mfma_i32_16x16x64_i8(ah[i], bl[j], cc[i][j], 0, 0, 0);
    __builtin_amdgcn_s_setprio(0);

    // ---- P3: cc pass 2 (al * bh) ----
    if (ks < 15) asm volatile("s_waitcnt vmcnt(6)" ::: "memory");
    else         asm volatile("s_waitcnt vmcnt(0)" ::: "memory");
    barrier_raw();
    if (ks < 15) stage_Al(ks + 1, buf ^ 1);

    int4v al[4];
#pragma unroll
    for (int i = 0; i < 4; ++i)
      al[i] = *(const int4v*)(sAl + buf * 8192 +
                              (wm * 64 + i * 16 + t16) * 64 + quad * 16);

    __builtin_amdgcn_s_setprio(1);
#pragma unroll
    for (int i = 0; i < 4; ++i)
#pragma unroll
      for (int j = 0; j < 4; ++j)
        cc[i][j] = __builtin_amdgcn_mfma_i32_16x16x64_i8(al[i], bh[j], cc[i][j], 0, 0, 0);
    __builtin_amdgcn_s_setprio(0);

    buf ^= 1;
  }

  // ---- epilogue: tile-local softmax stats + LDS-image E store -------------
  float* red = (float*)smem;  // buf-0 Ahi region; step-15 reads were buf 1

  float vv[4][4][4];
  float rmax[4][4];
#pragma unroll
  for (int i = 0; i < 4; ++i)
#pragma unroll
    for (int r = 0; r < 4; ++r) {
      float mx = -3.0e38f;
#pragma unroll
      for (int j = 0; j < 4; ++j) {
        float v = C_HH * (float)hh[i][j][r] + C_X * (float)cc[i][j][r];
        vv[i][j][r] = v;
        mx = fmaxf(mx, v);
      }
      mx = fmaxf(mx, __shfl_xor(mx, 1));
      mx = fmaxf(mx, __shfl_xor(mx, 2));
      mx = fmaxf(mx, __shfl_xor(mx, 4));
      mx = fmaxf(mx, __shfl_xor(mx, 8));
      rmax[i][r] = mx;
    }
  if (t16 == 0) {
#pragma unroll
    for (int i = 0; i < 4; ++i)
#pragma unroll
      for (int r = 0; r < 4; ++r)
        red[wn * 128 + wm * 64 + i * 16 + quad * 4 + r] = rmax[i][r];
  }
  __syncthreads();

  float mrow[4][4];
#pragma unroll
  for (int i = 0; i < 4; ++i)
#pragma unroll
    for (int r = 0; r < 4; ++r) {
      const int row = wm * 64 + i * 16 + quad * 4 + r;
      mrow[i][r] = fmaxf(red[row], red[128 + row]);
    }

  float rsum[4][4];
#pragma unroll
  for (int i = 0; i < 4; ++i)
#pragma unroll
    for (int r = 0; r < 4; ++r) {
      float s = 0.f;
#pragma unroll
      for (int j = 0; j < 4; ++j) {
        float e = __expf(vv[i][j][r] - mrow[i][r]);
        vv[i][j][r] = e;
        s += e;
      }
      s += __shfl_xor(s, 1);
      s += __shfl_xor(s, 2);
      s += __shfl_xor(s, 4);
      s += __shfl_xor(s, 8);
      rsum[i][r] = s;
    }
  if (t16 == 0) {
#pragma unroll
    for (int i = 0; i < 4; ++i)
#pragma unroll
      for (int r = 0; r < 4; ++r)
        red[256 + wn * 128 + wm * 64 + i * 16 + quad * 4 + r] = rsum[i][r];
  }

  // E fragments -> swizzled u16 image (overlays sBh/sBl: dead after K loop)
  uint16_t* img = (uint16_t*)(smem + 32768);  // [128][128] u16 = 32 KB
#pragma unroll
  for (int i = 0; i < 4; ++i)
#pragma unroll
    for (int j = 0; j < 4; ++j)
#pragma unroll
      for (int r = 0; r < 4; ++r) {
        const int row  = wm * 64 + i * 16 + quad * 4 + r;
        const int col  = wn * 64 + j * 16 + t16;
        const int colS = col ^ (((quad << 1) ^ r) << 3);
        _Float16 h = (_Float16)vv[i][j][r];
        img[row * 128 + colS] = *(const uint16_t*)&h;
      }
  __syncthreads();  // covers red-sum writes AND img writes

  // coalesced E store: 8 x b128 per thread
#pragma unroll
  for (int it = 0; it < 8; ++it) {
    const int row    = wave * 32 + it * 4 + quad;
    const int chunkS = t16 ^ swz3(row);
    int4v v = *(const int4v*)&img[row * 128 + chunkS * 8];
    *(int4v*)&E[(size_t)(row0 + row) * 4096 + col0 + t16 * 8] = v;
  }

  if (wn == 0 && t16 == 0) {
#pragma unroll
    for (int i = 0; i < 4; ++i)
#pragma unroll
      for (int r = 0; r < 4; ++r) {
        const int row = wm * 64 + i * 16 + quad * 4 + r;
        const float l = red[256 + row] + red[256 + 128 + row];
        stats[(size_t)(row0 + row) * 32 + blockIdx.x] =
            make_float2(mrow[i][r], l);
      }
  }
}

// ---------------------------------------------------------------------------
// proj: qk = x Wqk^T + bias. Same 3-phase K-step as s_stats.
__global__ __launch_bounds__(256, 2) void gemm_proj_i8(
    const int8_t* __restrict__ Ahi, const int8_t* __restrict__ Alo,
    const int8_t* __restrict__ Bhi, const int8_t* __restrict__ Blo,
    const float* __restrict__ biasQ, const float* __restrict__ biasK,
    int8_t* __restrict__ Ch, int8_t* __restrict__ Cl)
{
  __shared__ __align__(16) int8_t smem[65536];
  int8_t* sAh = smem;
  int8_t* sAl = smem + 16384;
  int8_t* sBh = smem + 32768;
  int8_t* sBl = smem + 49152;

  const int tid  = threadIdx.x;
  const int wave = tid >> 6;
  const int lane = tid & 63;
  const int quad = lane >> 4;
  const int t16  = lane & 15;
  const int wm   = wave & 1;
  const int wn   = wave >> 1;
  const int row0 = blockIdx.y * 128;
  const int col0 = blockIdx.x * 128;

  const int seg  = lane & 3;
  const int rsub = lane >> 2;

  const int offA0 = (row0 + wave * 16 + rsub) * 1024 + seg * 16;
  const int offA1 = offA0 + 64 * 1024;
  const int offB0 = (col0 + wave * 16 + rsub) * 1024 + seg * 16;
  const int offB1 = offB0 + 64 * 1024;
  const int ldsT0 = (wave * 16) * 64;
  const int ldsT1 = (64 + wave * 16) * 64;

  int4v hh[4][4], cc[4][4];
#pragma unroll
  for (int i = 0; i < 4; ++i)
#pragma unroll
    for (int j = 0; j < 4; ++j) {
      hh[i][j] = (int4v){0, 0, 0, 0};
      cc[i][j] = (int4v){0, 0, 0, 0};
    }

  auto stage_AhBh = [&](int ks, int b) {
    const int k0 = ks * 64;
    GLOAD_LDS16(Ahi + offA0 + k0, sAh + b * 8192 + ldsT0);
    GLOAD_LDS16(Ahi + offA1 + k0, sAh + b * 8192 + ldsT1);
    GLOAD_LDS16(Bhi + offB0 + k0, sBh + b * 8192 + ldsT0);
    GLOAD_LDS16(Bhi + offB1 + k0, sBh + b * 8192 + ldsT1);
  };
  auto stage_Bl = [&](int ks, int b) {
    const int k0 = ks * 64;
    GLOAD_LDS16(Blo + offB0 + k0, sBl + b * 8192 + ldsT0);
    GLOAD_LDS16(Blo + offB1 + k0, sBl + b * 8192 + ldsT1);
  };
  auto stage_Al = [&](int ks, int b) {
    const int k0 = ks * 64;
    GLOAD_LDS16(Alo + offA0 + k0, sAl + b * 8192 + ldsT0);
    GLOAD_LDS16(Alo + offA1 + k0, sAl + b * 8192 + ldsT1);
  };

  stage_AhBh(0, 0);
  stage_Bl(0, 0);
  stage_Al(0, 0);

  int buf = 0;
  for (int ks = 0; ks < 16; ++ks) {
    // ---- P1 ----
    asm volatile("s_waitcnt vmcnt(4)" ::: "memory");
    barrier_raw();
    if (ks < 15) stage_AhBh(ks + 1, buf ^ 1);

    int4v ah[4], bh[4];
#pragma unroll
    for (int i = 0; i < 4; ++i)
      ah[i] = *(const int4v*)(sAh + buf * 8192 +
                              (wm * 64 + i * 16 + t16) * 64 + quad * 16);
#pragma unroll
    for (int j = 0; j < 4; ++j)
      bh[j] = *(const int4v*)(sBh + buf * 8192 +
                              (wn * 64 + j * 16 + t16) * 64 + quad * 16);

    __builtin_amdgcn_s_setprio(1);
#pragma unroll
    for (int i = 0; i < 4; ++i)
#pragma unroll
      for (int j = 0; j < 4; ++j)
        hh[i][j] = __builtin_amdgcn_mfma_i32_16x16x64_i8(ah[i], bh[j], hh[i][j], 0, 0, 0);
    __builtin_amdgcn_s_setprio(0);

    // ---- P2 ----
    if (ks < 15) asm volatile("s_waitcnt vmcnt(6)" ::: "memory");
    else         asm volatile("s_waitcnt vmcnt(2)" ::: "memory");
    barrier_raw();
    if (ks < 15) stage_Bl(ks + 1, buf ^ 1);

    int4v bl[4];
#pragma unroll
    for (int j = 0; j < 4; ++j)
      bl[j] = *(const int4v*)(sBl + buf * 8192 +
                              (wn * 64 + j * 16 + t16) * 64 + quad * 16);

    __builtin_amdgcn_s_setprio(1);
#pragma unroll
    for (int i = 0; i < 4; ++i)
#pragma unroll
      for (int j = 0; j < 4; ++j)
        cc[i][j] = __builtin_amdgcn_mfma_i32_16x16x64_i8(ah[i], bl[j], cc[i][j], 0, 0, 0);
    __builtin_amdgcn_s_setprio(0);

    // ---- P3 ----
    if (ks < 15) asm volatile("s_waitcnt vmcnt(6)" ::: "memory");
    else         asm volatile("s_waitcnt vmcnt(0)" ::: "memory");
    barrier_raw();
    if (ks < 15) stage_Al(ks + 1, buf ^ 1);

    int4v al[4];
#pragma unroll
    for (int i = 0; i < 4; ++i)
      al[i] = *(const int4v*)(sAl + buf * 8192 +
                              (wm * 64 + i * 16 + t16) * 64 + quad * 16);

    __builtin_amdgcn_s_setprio(1);
#pragma unroll
    for (int i = 0; i < 4; ++i)
#pragma unroll
      for (int j = 0; j < 4; ++j)
        cc[i][j] = __builtin_amdgcn_mfma_i32_16x16x64_i8(al[i], bh[j], cc[i][j], 0, 0, 0);
    __builtin_amdgcn_s_setprio(0);

    buf ^= 1;
  }

  // ---- epilogue: quant -> packed u16 image -> coalesced plane stores ------
  uint16_t* img = (uint16_t*)(smem + 32768);  // [128][128] u16
#pragma unroll
  for (int i = 0; i < 4; ++i) {
#pragma unroll
    for (int j = 0; j < 4; ++j) {
      const int ccol = col0 + wn * 64 + j * 16 + t16;
      const float* bp = (ccol < 1024) ? biasQ : (biasK - 1024);
#pragma unroll
      for (int r = 0; r < 4; ++r) {
        float v = P_HH * (float)hh[i][j][r] + P_X * (float)cc[i][j][r] + bp[ccol];
        int hi = (int)lrintf(v * INV_S256);
        hi = hi > 127 ? 127 : (hi < -127 ? -127 : hi);
        int lo = (int)lrintf(v * INV_S - 256.0f * (float)hi);
        lo = lo > 127 ? 127 : (lo < -127 ? -127 : lo);
        const int row  = wm * 64 + i * 16 + quad * 4 + r;
        const int col  = wn * 64 + j * 16 + t16;
        const int colS = col ^ (((quad << 1) ^ r) << 3);
        img[row * 128 + colS] = (uint16_t)((hi & 0xff) | ((lo & 0xff) << 8));
      }
    }
  }
  __syncthreads();

#pragma unroll
  for (int it = 0; it < 8; ++it) {
    const int row    = wave * 32 + it * 4 + quad;
    const int chunkS = t16 ^ swz3(row);
    int4v p = *(const int4v*)&img[row * 128 + chunkS * 8];
    const unsigned w0 = (unsigned)p[0], w1 = (unsigned)p[1];
    const unsigned w2 = (unsigned)p[2], w3 = (unsigned)p[3];
    uint2v hw, lw;
    hw[0] = (w0 & 0xffu) | (((w0 >> 16) & 0xffu) << 8) |
            ((w1 & 0xffu) << 16) | (((w1 >> 16) & 0xffu) << 24);
    hw[1] = (w2 & 0xffu) | (((w2 >> 16) & 0xffu) << 8) |
            ((w3 & 0xffu) << 16) | (((w3 >> 16) & 0xffu) << 24);
    lw[0] = ((w0 >> 8) & 0xffu) | (((w0 >> 24) & 0xffu) << 8) |
            (((w1 >> 8) & 0xffu) << 16) | ((w1 >> 24) << 24);
    lw[1] = ((w2 >> 8) & 0xffu) | (((w2 >> 24) & 0xffu) << 8) |
            (((w3 >> 8) & 0xffu) << 16) | ((w3 >> 24) << 24);
    const size_t go = (size_t)(row0 + row) * 2048 + col0 + t16 * 8;
    *(uint2v*)&Ch[go] = hw;
    *(uint2v*)&Cl[go] = lw;
  }
}

// ---------------------------------------------------------------------------
// AV: out = sum_t beta_t (E_t x). R12 implementation (reverted from R14).
// 512 thr, in-block split-K=2; K-chunk 64; E+xT staged via global_load_lds;
// chunk-rotate LDS swizzle; one vmcnt(0)+barrier per step; fp32 image store.
__global__ __launch_bounds__(512) void gemm_av(
    const uint16_t* __restrict__ E, const uint16_t* __restrict__ B,
    const float2* __restrict__ stats, float* __restrict__ out)
{
  // [buf][z][ A:128x64h | B:128x64h ] = 128 KB
  __shared__ __align__(16) uint16_t stg[2][2][16384];
  __shared__ float betaS[128 * 33];

  const int L      = blockIdx.x;        // 0..255
  const int xcd    = L & 7;
  const int rest   = L >> 3;            // 0..31
  const int colb   = rest & 7;          // 0..7
  const int bandHi = rest >> 3;         // 0..3
  const int band   = xcd + 8 * bandHi;  // 0..31
  const int row0   = band * 128;
  const int col0   = colb * 128;

  const int tid  = threadIdx.x;
  const int wave = tid >> 6;
  const int z    = wave >> 2;           // wave-group = K-half
  const int gw   = wave & 3;            // group-local wave
  const int lane = tid & 63;
  const int quad = lane >> 4;
  const int t16  = lane & 15;
  const int wm   = gw & 1;
  const int wn   = gw >> 1;

  const int c8   = lane & 7;            // 16B-chunk within 128B row
  const int r8   = lane >> 3;           // row within 8-row stripe
  const int srcC = (c8 - r8) & 7;       // rotate: LDS[row][c] = glob[(c-row)&7]

  int offA[4], offB[4];
#pragma unroll
  for (int r = 0; r < 4; ++r) {
    offA[r] = (row0 + r * 32 + gw * 8 + r8) * 4096 + srcC * 8;
    offB[r] = (col0 + r * 32 + gw * 8 + r8) * 4096 + srcC * 8;
  }

  auto stage_s = [&](int s, int b) {
    const int k0h = (z * 16 + (s >> 1)) * 128 + (s & 1) * 64;
    uint16_t* sA = &stg[b][z][0];
    uint16_t* sB = &stg[b][z][8192];
#pragma unroll
    for (int r = 0; r < 4; ++r) {
      GLOAD_LDS16(E + offA[r] + k0h, &sA[(r * 32 + gw * 8) * 64]);
      GLOAD_LDS16(B + offB[r] + k0h, &sB[(r * 32 + gw * 8) * 64]);
    }
  };

  stage_s(0, 0);  // latency hides under the beta prologue

  if (tid < 128) {
    const int row = row0 + tid;
    float2 st[32];
    float m = -3.0e38f;
#pragma unroll
    for (int t = 0; t < 32; ++t) {
      st[t] = stats[(size_t)row * 32 + t];
      m = fmaxf(m, st[t].x);
    }
    float l = 0.f;
#pragma unroll
    for (int t = 0; t < 32; ++t) l += st[t].y * __expf(st[t].x - m);
    const float inv = 1.0f / l;
#pragma unroll
    for (int t = 0; t < 32; ++t)
      betaS[tid * 33 + t] = __expf(st[t].x - m) * inv;
  }
  asm volatile("s_waitcnt vmcnt(0)" ::: "memory");
  __syncthreads();

  float4v acc[4][4];
#pragma unroll
  for (int i = 0; i < 4; ++i)
#pragma unroll
    for (int j = 0; j < 4; ++j)
      acc[i][j] = (float4v){0.f, 0.f, 0.f, 0.f};

  int buf = 0;
  for (int s = 0; s < 32; ++s) {
    if (s < 31) stage_s(s + 1, buf ^ 1);

    const int t = z * 16 + (s >> 1);
    _Float16 bb[4];
#pragma unroll
    for (int i = 0; i < 4; ++i)
      bb[i] = (_Float16)betaS[(wm * 64 + i * 16 + t16) * 33 + t];

    const uint16_t* sA = &stg[buf][z][0];
    const uint16_t* sB = &stg[buf][z][8192];

    half8 af[2][4], bf[2][4];
#pragma unroll
    for (int ks = 0; ks < 2; ++ks) {
#pragma unroll
      for (int i = 0; i < 4; ++i) {
        const int row = wm * 64 + i * 16 + t16;
        const int ch  = (ks * 4 + quad + (t16 & 7)) & 7;
        af[ks][i] = *(const half8*)&sA[row * 64 + ch * 8];
        half8 bs;
#pragma unroll
        for (int c = 0; c < 8; ++c) bs[c] = bb[i];
        af[ks][i] = af[ks][i] * bs;
      }
#pragma unroll
      for (int j = 0; j < 4; ++j) {
        const int row = wn * 64 + j * 16 + t16;
        const int ch  = (ks * 4 + quad + (t16 & 7)) & 7;
        bf[ks][j] = *(const half8*)&sB[row * 64 + ch * 8];
      }
    }

    __builtin_amdgcn_s_setprio(1);
#pragma unroll
    for (int ks = 0; ks < 2; ++ks)
#pragma unroll
      for (int i = 0; i < 4; ++i)
#pragma unroll
        for (int j = 0; j < 4; ++j)
          acc[i][j] = __builtin_amdgcn_mfma_f32_16x16x32_f16(af[ks][i], bf[ks][j], acc[i][j], 0, 0, 0);
    __builtin_amdgcn_s_setprio(0);

    if (s < 31) asm volatile("s_waitcnt vmcnt(0)" ::: "memory");
    barrier_raw();
    buf ^= 1;
  }

  // ---- combine group1 -> group0 via LDS (two 32 KB halves) ----------------
  float* xfer = (float*)stg;  // bytes [0, 32K)
#pragma unroll
  for (int h = 0; h < 2; ++h) {
    if (z == 1) {
#pragma unroll
      for (int i = 2 * h; i < 2 * h + 2; ++i)
#pragma unroll
        for (int j = 0; j < 4; ++j)
#pragma unroll
          for (int r = 0; r < 4; ++r) {
            const int e = (i - 2 * h) * 16 + j * 4 + r;
            xfer[e * 256 + gw * 64 + lane] = acc[i][j][r];
          }
    }
    __syncthreads();
    if (z == 0) {
#pragma unroll
      for (int i = 2 * h; i < 2 * h + 2; ++i)
#pragma unroll
        for (int j = 0; j < 4; ++j)
#pragma unroll
          for (int r = 0; r < 4; ++r) {
            const int e = (i - 2 * h) * 16 + j * 4 + r;
            acc[i][j][r] += xfer[e * 256 + gw * 64 + lane];
          }
    }
    __syncthreads();
  }

  // ---- fp32 image store: z=0 writes image, ALL 512 threads store ----------
  float* img = (float*)((int8_t*)stg + 65536);  // [128][128] f32 = 64 KB
  if (z == 0) {
#pragma unroll
    for (int i = 0; i < 4; ++i)
#pragma unroll
      for (int j = 0; j < 4; ++j)
#pragma unroll
        for (int r = 0; r < 4; ++r) {
          const int row  = wm * 64 + i * 16 + quad * 4 + r;
          const int col  = wn * 64 + j * 16 + t16;
          const int colS = col ^ (((quad << 1) ^ r) << 2);
          img[row * 128 + colS] = acc[i][j][r];
        }
  }
  __syncthreads();

#pragma unroll
  for (int it = 0; it < 8; ++it) {
    const int row    = wave * 16 + (lane >> 2);
    const int chunk  = (lane & 3) * 8 + it;          // 32 chunks of 4 floats
    const int chunkS = chunk ^ swz3(row);
    float4v v = *(const float4v*)&img[row * 128 + chunkS * 4];
    *(float4v*)&out[(size_t)(row0 + row) * 1024 + col0 + chunk * 4] = v;
  }
}

// ---------------------------------------------------------------------------
// Fused quant + transpose-cast (unchanged).
__global__ __launch_bounds__(256) void quantT(
    const float* __restrict__ x, const float* __restrict__ Wq,
    const float* __restrict__ Wk,
    int8_t* __restrict__ xhi, int8_t* __restrict__ xlo,
    int8_t* __restrict__ whi, int8_t* __restrict__ wlo,
    uint16_t* __restrict__ xT)
{
  if (blockIdx.x < 6144) {
    int i = blockIdx.x * 256 + threadIdx.x;  // 0..1572863
    const float* src; int8_t* dh; int8_t* dl; int idx; float s256, s;
    if (i < 1048576)      { src = x;  idx = i;           dh = xhi; dl = xlo;
                            s256 = INV_S256; s = INV_S; }
    else if (i < 1310720) { src = Wq; idx = i - 1048576; dh = whi; dl = wlo;
                            s256 = 512.0f; s = 131072.0f; }
    else                  { src = Wk; idx = i - 1310720; dh = whi + 1048576;
                            dl = wlo + 1048576; s256 = 512.0f; s = 131072.0f; }
    float4 v = ((const float4*)src)[idx];
    float vv[4] = {v.x, v.y, v.z, v.w};
    int hp = 0, lp = 0;
#pragma unroll
    for (int c = 0; c < 4; ++c) {
      int h = (int)lrintf(vv[c] * s256);
      h = h > 127 ? 127 : (h < -127 ? -127 : h);
      int l = (int)lrintf(vv[c] * s - 256.0f * (float)h);
      l = l > 127 ? 127 : (l < -127 ? -127 : l);
      hp |= (h & 0xff) << (8 * c);
      lp |= (l & 0xff) << (8 * c);
    }
    ((int*)dh)[idx] = hp;
    ((int*)dl)[idx] = lp;
  } else {
    __shared__ float tile[32][33];
    const int tb = blockIdx.x - 6144;   // 0..4095
    const int bx = tb & 31;             // D/32
    const int by = tb >> 5;             // N/32
    const int tx = threadIdx.x & 31;
    const int ty = threadIdx.x >> 5;    // 0..7
#pragma unroll
    for (int p = 0; p < 4; ++p) {
      const int row = by * 32 + ty + p * 8;
      tile[ty + p * 8][tx] = x[(size_t)row * 1024 + bx * 32 + tx];
    }
    __syncthreads();
#pragma unroll
    for (int p = 0; p < 4; ++p) {
      const int oc = ty + p * 8;  // local col in x == local row in xT
      __half hv = __float2half_rn(tile[tx][oc]);
      xT[(size_t)(bx * 32 + oc) * 4096 + by * 32 + tx] = *(uint16_t*)&hv;
    }
  }
}

extern "C" void kernel_launch(void* const* d_in, const int* in_sizes, int n_in,
                              void* d_out, int out_size, void* d_ws, size_t ws_size,
                              hipStream_t stream) {
  const int N = 4096, D = 1024;
  const float* x  = (const float*)d_in[0];
  const float* Wq = (const float*)d_in[1];
  const float* bq = (const float*)d_in[2];
  const float* Wk = (const float*)d_in[3];
  const float* bk = (const float*)d_in[4];
  float* out = (float*)d_out;

  // workspace layout (MiB offsets)
  char* w = (char*)d_ws;
  const size_t MiB = 1024 * 1024;
  int8_t*    xq_hi  = (int8_t*)   (w + 0  * MiB);  // [N x D]
  int8_t*    xq_lo  = (int8_t*)   (w + 4  * MiB);
  int8_t*    Wqk_hi = (int8_t*)   (w + 8  * MiB);  // [2048 x D]
  int8_t*    Wqk_lo = (int8_t*)   (w + 10 * MiB);
  int8_t*    qk_hi  = (int8_t*)   (w + 12 * MiB);  // [N x 2048]
  int8_t*    qk_lo  = (int8_t*)   (w + 20 * MiB);
  _Float16*  E      = (_Float16*) (w + 36 * MiB);  // [N x N] fp16, 32 MiB
  float2*    stats  = (float2*)   (w + 68 * MiB);  // [N x 32] (m,l), 1 MiB
  uint16_t*  xTh    = (uint16_t*) (w + 72 * MiB);  // [D x N] fp16
  // total 80 MiB

  // 1) fused quantization + transpose-cast  (6144 + 4096 blocks)
  quantT<<<10240, 256, 0, stream>>>(x, Wq, Wk, xq_hi, xq_lo, Wqk_hi, Wqk_lo,
                                    xTh);

  // 2) fused qk projection: i8 16x16x64, 3-phase K-step
  gemm_proj_i8<<<dim3(2048 / 128, N / 128), 256, 0, stream>>>(
      xq_hi, xq_lo, Wqk_hi, Wqk_lo, bq, bk, qk_hi, qk_lo);

  // 3) S = q k^T + tile softmax stats -> E fp16, stats (m_t, l_t)
  gemm_s_stats<<<dim3(N / 128, N / 128), 256, 0, stream>>>(
      qk_hi, qk_lo, qk_hi + 1024, qk_lo + 1024, E, stats);

  // 4) out = sum_t beta_t (E_t x): beta prologue + in-block split-K=2
  gemm_av<<<256, 512, 0, stream>>>((const uint16_t*)E, xTh, stats, out);

  (void)in_sizes; (void)n_in; (void)out_size; (void)ws_size;
}

// Round 7
// 212.477 us; speedup vs baseline: 1.2550x; 1.0128x over previous
//
#include <hip/hip_runtime.h>
#include <hip/hip_bf16.h>
#include <hip/hip_fp16.h>
#include <stdint.h>

// ---------------------------------------------------------------------------
// CLIPAttentionPooling. R16: av re-tiled for 2 blocks/CU anti-phasing.
// R15 kept verbatim for s_stats/proj (3-phase K-step, total 215.2 best).
// av: 512 blocks x 256 thr, 128x64 tiles, NO split-K (xfer epilogue gone),
// 2 x 24KB bufs + fp16 betaS = 57.6 KB -> 2 blocks/CU, independent barrier
// domains anti-phase MFMA vs stage/ds_read. XCD swizzle groups one band's
// 16 col-blocks on one XCD (E re-reads are L2-local).
// ---------------------------------------------------------------------------

using half8   = __attribute__((ext_vector_type(8))) _Float16;
using float4v = __attribute__((ext_vector_type(4))) float;
using int4v   = __attribute__((ext_vector_type(4))) int;
using uint2v  = __attribute__((ext_vector_type(2))) unsigned int;

// q/k int16 grid: covers +-6.0, v = QS*(256*hi+lo)
#define QS        (6.0f / 32768.0f)
#define INV_S     (32768.0f / 6.0f)
#define INV_S256  (128.0f / 6.0f)
#define C_HH      (65536.0f * QS * QS)
#define C_X       (256.0f * QS * QS)

// x grid: +-6.0 ; W grid: +-0.25
#define SX        (6.0f / 32768.0f)
#define SW        (0.25f / 32768.0f)
#define P_HH      (65536.0f * SX * SW)
#define P_X       (256.0f * SX * SW)

#define GLOAD_LDS16(gptr, ldsptr)                                              \
  __builtin_amdgcn_global_load_lds(                                            \
      (__attribute__((address_space(1))) void*)(uintptr_t)(gptr),              \
      (__attribute__((address_space(3))) void*)(unsigned)(uintptr_t)(ldsptr),  \
      16, 0, 0)

__device__ __forceinline__ void barrier_raw() {
  asm volatile("" ::: "memory");
  __builtin_amdgcn_s_barrier();
  asm volatile("" ::: "memory");
}

// chunk-level swizzle for the epilogue images (R12-proven).
__device__ __forceinline__ int swz3(int row) {
  return (((row >> 2) & 3) << 1) ^ (row & 3);
}

// ---------------------------------------------------------------------------
// S GEMM + tile softmax stats. Split-i8 16x16x64, 128x128 tile, BK=64.
// R15 3-phase K-step (unchanged).
__global__ __launch_bounds__(256, 2) void gemm_s_stats(
    const int8_t* __restrict__ Ahi, const int8_t* __restrict__ Alo,
    const int8_t* __restrict__ Bhi, const int8_t* __restrict__ Blo,
    _Float16* __restrict__ E, float2* __restrict__ stats)
{
  __shared__ __align__(16) int8_t smem[65536];
  int8_t* sAh = smem;            // [2][8192]
  int8_t* sAl = smem + 16384;    // [2][8192]
  int8_t* sBh = smem + 32768;    // [2][8192]
  int8_t* sBl = smem + 49152;    // [2][8192]

  const int tid  = threadIdx.x;
  const int wave = tid >> 6;
  const int lane = tid & 63;
  const int quad = lane >> 4;
  const int t16  = lane & 15;
  const int wm   = wave & 1;
  const int wn   = wave >> 1;
  const int row0 = blockIdx.y * 128;
  const int col0 = blockIdx.x * 128;

  const int seg  = lane & 3;   // 16B chunk within 64B row
  const int rsub = lane >> 2;  // row within 16-row stripe

  const int offA0 = (row0 + wave * 16 + rsub) * 2048 + seg * 16;
  const int offA1 = offA0 + 64 * 2048;
  const int offB0 = (col0 + wave * 16 + rsub) * 2048 + seg * 16;
  const int offB1 = offB0 + 64 * 2048;
  const int ldsT0 = (wave * 16) * 64;
  const int ldsT1 = (64 + wave * 16) * 64;

  int4v hh[4][4], cc[4][4];
#pragma unroll
  for (int i = 0; i < 4; ++i)
#pragma unroll
    for (int j = 0; j < 4; ++j) {
      hh[i][j] = (int4v){0, 0, 0, 0};
      cc[i][j] = (int4v){0, 0, 0, 0};
    }

  auto stage_AhBh = [&](int ks, int b) {
    const int k0 = ks * 64;
    GLOAD_LDS16(Ahi + offA0 + k0, sAh + b * 8192 + ldsT0);
    GLOAD_LDS16(Ahi + offA1 + k0, sAh + b * 8192 + ldsT1);
    GLOAD_LDS16(Bhi + offB0 + k0, sBh + b * 8192 + ldsT0);
    GLOAD_LDS16(Bhi + offB1 + k0, sBh + b * 8192 + ldsT1);
  };
  auto stage_Bl = [&](int ks, int b) {
    const int k0 = ks * 64;
    GLOAD_LDS16(Blo + offB0 + k0, sBl + b * 8192 + ldsT0);
    GLOAD_LDS16(Blo + offB1 + k0, sBl + b * 8192 + ldsT1);
  };
  auto stage_Al = [&](int ks, int b) {
    const int k0 = ks * 64;
    GLOAD_LDS16(Alo + offA0 + k0, sAl + b * 8192 + ldsT0);
    GLOAD_LDS16(Alo + offA1 + k0, sAl + b * 8192 + ldsT1);
  };

  stage_AhBh(0, 0);
  stage_Bl(0, 0);
  stage_Al(0, 0);

  int buf = 0;
  for (int ks = 0; ks < 16; ++ks) {
    // ---- P1: hh pass ----
    asm volatile("s_waitcnt vmcnt(4)" ::: "memory");
    barrier_raw();
    if (ks < 15) stage_AhBh(ks + 1, buf ^ 1);

    int4v ah[4], bh[4];
#pragma unroll
    for (int i = 0; i < 4; ++i)
      ah[i] = *(const int4v*)(sAh + buf * 8192 +
                              (wm * 64 + i * 16 + t16) * 64 + quad * 16);
#pragma unroll
    for (int j = 0; j < 4; ++j)
      bh[j] = *(const int4v*)(sBh + buf * 8192 +
                              (wn * 64 + j * 16 + t16) * 64 + quad * 16);

    __builtin_amdgcn_s_setprio(1);
#pragma unroll
    for (int i = 0; i < 4; ++i)
#pragma unroll
      for (int j = 0; j < 4; ++j)
        hh[i][j] = __builtin_amdgcn_mfma_i32_16x16x64_i8(ah[i], bh[j], hh[i][j], 0, 0, 0);
    __builtin_amdgcn_s_setprio(0);

    // ---- P2: cc pass 1 (ah * bl) ----
    if (ks < 15) asm volatile("s_waitcnt vmcnt(6)" ::: "memory");
    else         asm volatile("s_waitcnt vmcnt(2)" ::: "memory");
    barrier_raw();
    if (ks < 15) stage_Bl(ks + 1, buf ^ 1);

    int4v bl[4];
#pragma unroll
    for (int j = 0; j < 4; ++j)
      bl[j] = *(const int4v*)(sBl + buf * 8192 +
                              (wn * 64 + j * 16 + t16) * 64 + quad * 16);

    __builtin_amdgcn_s_setprio(1);
#pragma unroll
    for (int i = 0; i < 4; ++i)
#pragma unroll
      for (int j = 0; j < 4; ++j)
        cc[i][j] = __builtin_amdgcn_mfma_i32_16x16x64_i8(ah[i], bl[j], cc[i][j], 0, 0, 0);
    __builtin_amdgcn_s_setprio(0);

    // ---- P3: cc pass 2 (al * bh) ----
    if (ks < 15) asm volatile("s_waitcnt vmcnt(6)" ::: "memory");
    else         asm volatile("s_waitcnt vmcnt(0)" ::: "memory");
    barrier_raw();
    if (ks < 15) stage_Al(ks + 1, buf ^ 1);

    int4v al[4];
#pragma unroll
    for (int i = 0; i < 4; ++i)
      al[i] = *(const int4v*)(sAl + buf * 8192 +
                              (wm * 64 + i * 16 + t16) * 64 + quad * 16);

    __builtin_amdgcn_s_setprio(1);
#pragma unroll
    for (int i = 0; i < 4; ++i)
#pragma unroll
      for (int j = 0; j < 4; ++j)
        cc[i][j] = __builtin_amdgcn_mfma_i32_16x16x64_i8(al[i], bh[j], cc[i][j], 0, 0, 0);
    __builtin_amdgcn_s_setprio(0);

    buf ^= 1;
  }

  // ---- epilogue: tile-local softmax stats + LDS-image E store -------------
  float* red = (float*)smem;  // buf-0 Ahi region; step-15 reads were buf 1

  float vv[4][4][4];
  float rmax[4][4];
#pragma unroll
  for (int i = 0; i < 4; ++i)
#pragma unroll
    for (int r = 0; r < 4; ++r) {
      float mx = -3.0e38f;
#pragma unroll
      for (int j = 0; j < 4; ++j) {
        float v = C_HH * (float)hh[i][j][r] + C_X * (float)cc[i][j][r];
        vv[i][j][r] = v;
        mx = fmaxf(mx, v);
      }
      mx = fmaxf(mx, __shfl_xor(mx, 1));
      mx = fmaxf(mx, __shfl_xor(mx, 2));
      mx = fmaxf(mx, __shfl_xor(mx, 4));
      mx = fmaxf(mx, __shfl_xor(mx, 8));
      rmax[i][r] = mx;
    }
  if (t16 == 0) {
#pragma unroll
    for (int i = 0; i < 4; ++i)
#pragma unroll
      for (int r = 0; r < 4; ++r)
        red[wn * 128 + wm * 64 + i * 16 + quad * 4 + r] = rmax[i][r];
  }
  __syncthreads();

  float mrow[4][4];
#pragma unroll
  for (int i = 0; i < 4; ++i)
#pragma unroll
    for (int r = 0; r < 4; ++r) {
      const int row = wm * 64 + i * 16 + quad * 4 + r;
      mrow[i][r] = fmaxf(red[row], red[128 + row]);
    }

  float rsum[4][4];
#pragma unroll
  for (int i = 0; i < 4; ++i)
#pragma unroll
    for (int r = 0; r < 4; ++r) {
      float s = 0.f;
#pragma unroll
      for (int j = 0; j < 4; ++j) {
        float e = __expf(vv[i][j][r] - mrow[i][r]);
        vv[i][j][r] = e;
        s += e;
      }
      s += __shfl_xor(s, 1);
      s += __shfl_xor(s, 2);
      s += __shfl_xor(s, 4);
      s += __shfl_xor(s, 8);
      rsum[i][r] = s;
    }
  if (t16 == 0) {
#pragma unroll
    for (int i = 0; i < 4; ++i)
#pragma unroll
      for (int r = 0; r < 4; ++r)
        red[256 + wn * 128 + wm * 64 + i * 16 + quad * 4 + r] = rsum[i][r];
  }

  // E fragments -> swizzled u16 image (overlays sBh/sBl: dead after K loop)
  uint16_t* img = (uint16_t*)(smem + 32768);  // [128][128] u16 = 32 KB
#pragma unroll
  for (int i = 0; i < 4; ++i)
#pragma unroll
    for (int j = 0; j < 4; ++j)
#pragma unroll
      for (int r = 0; r < 4; ++r) {
        const int row  = wm * 64 + i * 16 + quad * 4 + r;
        const int col  = wn * 64 + j * 16 + t16;
        const int colS = col ^ (((quad << 1) ^ r) << 3);
        _Float16 h = (_Float16)vv[i][j][r];
        img[row * 128 + colS] = *(const uint16_t*)&h;
      }
  __syncthreads();  // covers red-sum writes AND img writes

  // coalesced E store: 8 x b128 per thread
#pragma unroll
  for (int it = 0; it < 8; ++it) {
    const int row    = wave * 32 + it * 4 + quad;
    const int chunkS = t16 ^ swz3(row);
    int4v v = *(const int4v*)&img[row * 128 + chunkS * 8];
    *(int4v*)&E[(size_t)(row0 + row) * 4096 + col0 + t16 * 8] = v;
  }

  if (wn == 0 && t16 == 0) {
#pragma unroll
    for (int i = 0; i < 4; ++i)
#pragma unroll
      for (int r = 0; r < 4; ++r) {
        const int row = wm * 64 + i * 16 + quad * 4 + r;
        const float l = red[256 + row] + red[256 + 128 + row];
        stats[(size_t)(row0 + row) * 32 + blockIdx.x] =
            make_float2(mrow[i][r], l);
      }
  }
}

// ---------------------------------------------------------------------------
// proj: qk = x Wqk^T + bias. R15 3-phase K-step (unchanged).
__global__ __launch_bounds__(256, 2) void gemm_proj_i8(
    const int8_t* __restrict__ Ahi, const int8_t* __restrict__ Alo,
    const int8_t* __restrict__ Bhi, const int8_t* __restrict__ Blo,
    const float* __restrict__ biasQ, const float* __restrict__ biasK,
    int8_t* __restrict__ Ch, int8_t* __restrict__ Cl)
{
  __shared__ __align__(16) int8_t smem[65536];
  int8_t* sAh = smem;
  int8_t* sAl = smem + 16384;
  int8_t* sBh = smem + 32768;
  int8_t* sBl = smem + 49152;

  const int tid  = threadIdx.x;
  const int wave = tid >> 6;
  const int lane = tid & 63;
  const int quad = lane >> 4;
  const int t16  = lane & 15;
  const int wm   = wave & 1;
  const int wn   = wave >> 1;
  const int row0 = blockIdx.y * 128;
  const int col0 = blockIdx.x * 128;

  const int seg  = lane & 3;
  const int rsub = lane >> 2;

  const int offA0 = (row0 + wave * 16 + rsub) * 1024 + seg * 16;
  const int offA1 = offA0 + 64 * 1024;
  const int offB0 = (col0 + wave * 16 + rsub) * 1024 + seg * 16;
  const int offB1 = offB0 + 64 * 1024;
  const int ldsT0 = (wave * 16) * 64;
  const int ldsT1 = (64 + wave * 16) * 64;

  int4v hh[4][4], cc[4][4];
#pragma unroll
  for (int i = 0; i < 4; ++i)
#pragma unroll
    for (int j = 0; j < 4; ++j) {
      hh[i][j] = (int4v){0, 0, 0, 0};
      cc[i][j] = (int4v){0, 0, 0, 0};
    }

  auto stage_AhBh = [&](int ks, int b) {
    const int k0 = ks * 64;
    GLOAD_LDS16(Ahi + offA0 + k0, sAh + b * 8192 + ldsT0);
    GLOAD_LDS16(Ahi + offA1 + k0, sAh + b * 8192 + ldsT1);
    GLOAD_LDS16(Bhi + offB0 + k0, sBh + b * 8192 + ldsT0);
    GLOAD_LDS16(Bhi + offB1 + k0, sBh + b * 8192 + ldsT1);
  };
  auto stage_Bl = [&](int ks, int b) {
    const int k0 = ks * 64;
    GLOAD_LDS16(Blo + offB0 + k0, sBl + b * 8192 + ldsT0);
    GLOAD_LDS16(Blo + offB1 + k0, sBl + b * 8192 + ldsT1);
  };
  auto stage_Al = [&](int ks, int b) {
    const int k0 = ks * 64;
    GLOAD_LDS16(Alo + offA0 + k0, sAl + b * 8192 + ldsT0);
    GLOAD_LDS16(Alo + offA1 + k0, sAl + b * 8192 + ldsT1);
  };

  stage_AhBh(0, 0);
  stage_Bl(0, 0);
  stage_Al(0, 0);

  int buf = 0;
  for (int ks = 0; ks < 16; ++ks) {
    // ---- P1 ----
    asm volatile("s_waitcnt vmcnt(4)" ::: "memory");
    barrier_raw();
    if (ks < 15) stage_AhBh(ks + 1, buf ^ 1);

    int4v ah[4], bh[4];
#pragma unroll
    for (int i = 0; i < 4; ++i)
      ah[i] = *(const int4v*)(sAh + buf * 8192 +
                              (wm * 64 + i * 16 + t16) * 64 + quad * 16);
#pragma unroll
    for (int j = 0; j < 4; ++j)
      bh[j] = *(const int4v*)(sBh + buf * 8192 +
                              (wn * 64 + j * 16 + t16) * 64 + quad * 16);

    __builtin_amdgcn_s_setprio(1);
#pragma unroll
    for (int i = 0; i < 4; ++i)
#pragma unroll
      for (int j = 0; j < 4; ++j)
        hh[i][j] = __builtin_amdgcn_mfma_i32_16x16x64_i8(ah[i], bh[j], hh[i][j], 0, 0, 0);
    __builtin_amdgcn_s_setprio(0);

    // ---- P2 ----
    if (ks < 15) asm volatile("s_waitcnt vmcnt(6)" ::: "memory");
    else         asm volatile("s_waitcnt vmcnt(2)" ::: "memory");
    barrier_raw();
    if (ks < 15) stage_Bl(ks + 1, buf ^ 1);

    int4v bl[4];
#pragma unroll
    for (int j = 0; j < 4; ++j)
      bl[j] = *(const int4v*)(sBl + buf * 8192 +
                              (wn * 64 + j * 16 + t16) * 64 + quad * 16);

    __builtin_amdgcn_s_setprio(1);
#pragma unroll
    for (int i = 0; i < 4; ++i)
#pragma unroll
      for (int j = 0; j < 4; ++j)
        cc[i][j] = __builtin_amdgcn_mfma_i32_16x16x64_i8(ah[i], bl[j], cc[i][j], 0, 0, 0);
    __builtin_amdgcn_s_setprio(0);

    // ---- P3 ----
    if (ks < 15) asm volatile("s_waitcnt vmcnt(6)" ::: "memory");
    else         asm volatile("s_waitcnt vmcnt(0)" ::: "memory");
    barrier_raw();
    if (ks < 15) stage_Al(ks + 1, buf ^ 1);

    int4v al[4];
#pragma unroll
    for (int i = 0; i < 4; ++i)
      al[i] = *(const int4v*)(sAl + buf * 8192 +
                              (wm * 64 + i * 16 + t16) * 64 + quad * 16);

    __builtin_amdgcn_s_setprio(1);
#pragma unroll
    for (int i = 0; i < 4; ++i)
#pragma unroll
      for (int j = 0; j < 4; ++j)
        cc[i][j] = __builtin_amdgcn_mfma_i32_16x16x64_i8(al[i], bh[j], cc[i][j], 0, 0, 0);
    __builtin_amdgcn_s_setprio(0);

    buf ^= 1;
  }

  // ---- epilogue: quant -> packed u16 image -> coalesced plane stores ------
  uint16_t* img = (uint16_t*)(smem + 32768);  // [128][128] u16
#pragma unroll
  for (int i = 0; i < 4; ++i) {
#pragma unroll
    for (int j = 0; j < 4; ++j) {
      const int ccol = col0 + wn * 64 + j * 16 + t16;
      const float* bp = (ccol < 1024) ? biasQ : (biasK - 1024);
#pragma unroll
      for (int r = 0; r < 4; ++r) {
        float v = P_HH * (float)hh[i][j][r] + P_X * (float)cc[i][j][r] + bp[ccol];
        int hi = (int)lrintf(v * INV_S256);
        hi = hi > 127 ? 127 : (hi < -127 ? -127 : hi);
        int lo = (int)lrintf(v * INV_S - 256.0f * (float)hi);
        lo = lo > 127 ? 127 : (lo < -127 ? -127 : lo);
        const int row  = wm * 64 + i * 16 + quad * 4 + r;
        const int col  = wn * 64 + j * 16 + t16;
        const int colS = col ^ (((quad << 1) ^ r) << 3);
        img[row * 128 + colS] = (uint16_t)((hi & 0xff) | ((lo & 0xff) << 8));
      }
    }
  }
  __syncthreads();

#pragma unroll
  for (int it = 0; it < 8; ++it) {
    const int row    = wave * 32 + it * 4 + quad;
    const int chunkS = t16 ^ swz3(row);
    int4v p = *(const int4v*)&img[row * 128 + chunkS * 8];
    const unsigned w0 = (unsigned)p[0], w1 = (unsigned)p[1];
    const unsigned w2 = (unsigned)p[2], w3 = (unsigned)p[3];
    uint2v hw, lw;
    hw[0] = (w0 & 0xffu) | (((w0 >> 16) & 0xffu) << 8) |
            ((w1 & 0xffu) << 16) | (((w1 >> 16) & 0xffu) << 24);
    hw[1] = (w2 & 0xffu) | (((w2 >> 16) & 0xffu) << 8) |
            ((w3 & 0xffu) << 16) | (((w3 >> 16) & 0xffu) << 24);
    lw[0] = ((w0 >> 8) & 0xffu) | (((w0 >> 24) & 0xffu) << 8) |
            (((w1 >> 8) & 0xffu) << 16) | ((w1 >> 24) << 24);
    lw[1] = ((w2 >> 8) & 0xffu) | (((w2 >> 24) & 0xffu) << 8) |
            (((w3 >> 8) & 0xffu) << 16) | ((w3 >> 24) << 24);
    const size_t go = (size_t)(row0 + row) * 2048 + col0 + t16 * 8;
    *(uint2v*)&Ch[go] = hw;
    *(uint2v*)&Cl[go] = lw;
  }
}

// ---------------------------------------------------------------------------
// AV: out = sum_t beta_t (E_t x). R16: 512 blocks x 256 thr, 128x64 tiles,
// no split-K. 2 x (A 16K | B 8K) bufs + fp16 betaS = 57.6 KB -> 2 blocks/CU.
// 64 steps of BK=64; one vmcnt(0)+barrier per step; chunk-rotate swizzle.
__global__ __launch_bounds__(256, 2) void gemm_av(
    const uint16_t* __restrict__ E, const uint16_t* __restrict__ B,
    const float2* __restrict__ stats, float* __restrict__ out)
{
  // [buf][ A:128x64h | B:64x64h ] = 2 x 24 KB
  __shared__ __align__(16) uint16_t stg[2][12288];
  __shared__ _Float16 betaS[128 * 33];   // 8.25 KB

  const int L      = blockIdx.x;        // 0..511
  const int xcd    = L & 7;
  const int rest   = L >> 3;            // 0..63
  const int colb   = rest & 15;         // 0..15
  const int bandHi = rest >> 4;         // 0..3
  const int band   = xcd + 8 * bandHi;  // 0..31
  const int row0   = band * 128;
  const int col0   = colb * 64;

  const int tid  = threadIdx.x;
  const int wave = tid >> 6;            // 0..3
  const int lane = tid & 63;
  const int quad = lane >> 4;
  const int t16  = lane & 15;
  const int wm   = wave & 1;
  const int wn   = wave >> 1;

  const int r8   = lane >> 3;           // row within 8-row stripe
  const int c8   = lane & 7;            // 16B chunk within 128B row
  const int srcC = (c8 - r8) & 7;       // rotate: LDS[row][c] = glob[(c-row)&7]

  // stage offsets in halves (+ s*64 per step)
  int offA[4], offBx[2];
#pragma unroll
  for (int p = 0; p < 4; ++p)
    offA[p] = (row0 + p * 32 + wave * 8 + r8) * 4096 + srcC * 8;
#pragma unroll
  for (int p = 0; p < 2; ++p)
    offBx[p] = (col0 + p * 32 + wave * 8 + r8) * 4096 + srcC * 8;

  auto stage_s = [&](int s, int b) {
    const int k0h = s * 64;
    uint16_t* sA = &stg[b][0];
    uint16_t* sB = &stg[b][8192];
#pragma unroll
    for (int p = 0; p < 4; ++p)
      GLOAD_LDS16(E + offA[p] + k0h, &sA[(p * 32 + wave * 8) * 64]);
#pragma unroll
    for (int p = 0; p < 2; ++p)
      GLOAD_LDS16(B + offBx[p] + k0h, &sB[(p * 32 + wave * 8) * 64]);
  };

  stage_s(0, 0);  // HBM latency hides under the beta prologue

  // ---- beta prologue: threads 0..127, one row each ------------------------
  if (tid < 128) {
    const int row = row0 + tid;
    float2 st[32];
    float m = -3.0e38f;
#pragma unroll
    for (int t = 0; t < 32; ++t) {
      st[t] = stats[(size_t)row * 32 + t];
      m = fmaxf(m, st[t].x);
    }
    float l = 0.f;
#pragma unroll
    for (int t = 0; t < 32; ++t) l += st[t].y * __expf(st[t].x - m);
    const float inv = 1.0f / l;
#pragma unroll
    for (int t = 0; t < 32; ++t)
      betaS[tid * 33 + t] = (_Float16)(__expf(st[t].x - m) * inv);
  }
  asm volatile("s_waitcnt vmcnt(0)" ::: "memory");
  __syncthreads();  // covers betaS AND stage(0)

  float4v acc[4][2];
#pragma unroll
  for (int i = 0; i < 4; ++i)
#pragma unroll
    for (int j = 0; j < 2; ++j)
      acc[i][j] = (float4v){0.f, 0.f, 0.f, 0.f};

  int buf = 0;
  for (int s = 0; s < 64; ++s) {
    if (s < 63) stage_s(s + 1, buf ^ 1);

    const int t = s >> 1;
    _Float16 bb[4];
#pragma unroll
    for (int i = 0; i < 4; ++i)
      bb[i] = betaS[(wm * 64 + i * 16 + t16) * 33 + t];

    const uint16_t* sA = &stg[buf][0];
    const uint16_t* sB = &stg[buf][8192];

    half8 af[2][4], bf[2][2];
#pragma unroll
    for (int ks = 0; ks < 2; ++ks) {
#pragma unroll
      for (int i = 0; i < 4; ++i) {
        const int row = wm * 64 + i * 16 + t16;
        const int ch  = (ks * 4 + quad + (t16 & 7)) & 7;
        af[ks][i] = *(const half8*)&sA[row * 64 + ch * 8];
        half8 bs;
#pragma unroll
        for (int c = 0; c < 8; ++c) bs[c] = bb[i];
        af[ks][i] = af[ks][i] * bs;
      }
#pragma unroll
      for (int j = 0; j < 2; ++j) {
        const int row = wn * 32 + j * 16 + t16;
        const int ch  = (ks * 4 + quad + (t16 & 7)) & 7;
        bf[ks][j] = *(const half8*)&sB[row * 64 + ch * 8];
      }
    }

    __builtin_amdgcn_s_setprio(1);
#pragma unroll
    for (int ks = 0; ks < 2; ++ks)
#pragma unroll
      for (int i = 0; i < 4; ++i)
#pragma unroll
        for (int j = 0; j < 2; ++j)
          acc[i][j] = __builtin_amdgcn_mfma_f32_16x16x32_f16(af[ks][i], bf[ks][j], acc[i][j], 0, 0, 0);
    __builtin_amdgcn_s_setprio(0);

    if (s < 63) asm volatile("s_waitcnt vmcnt(0)" ::: "memory");
    barrier_raw();
    buf ^= 1;
  }

  // ---- fp32 image store (no split-K combine needed) -----------------------
  float* img = (float*)stg;  // [128][64] f32 = 32 KB over the stage region
#pragma unroll
  for (int i = 0; i < 4; ++i)
#pragma unroll
    for (int j = 0; j < 2; ++j)
#pragma unroll
      for (int r = 0; r < 4; ++r) {
        const int row  = wm * 64 + i * 16 + quad * 4 + r;
        const int col  = wn * 32 + j * 16 + t16;
        const int colS = col ^ (swz3(row) << 2);
        img[row * 64 + colS] = acc[i][j][r];
      }
  __syncthreads();

#pragma unroll
  for (int it = 0; it < 8; ++it) {
    const int row    = wave * 32 + it * 4 + quad;
    const int chunkS = t16 ^ swz3(row);      // 16 chunks of 4 floats
    float4v v = *(const float4v*)&img[row * 64 + chunkS * 4];
    *(float4v*)&out[(size_t)(row0 + row) * 1024 + col0 + t16 * 4] = v;
  }
}

// ---------------------------------------------------------------------------
// Fused quant + transpose-cast (unchanged).
__global__ __launch_bounds__(256) void quantT(
    const float* __restrict__ x, const float* __restrict__ Wq,
    const float* __restrict__ Wk,
    int8_t* __restrict__ xhi, int8_t* __restrict__ xlo,
    int8_t* __restrict__ whi, int8_t* __restrict__ wlo,
    uint16_t* __restrict__ xT)
{
  if (blockIdx.x < 6144) {
    int i = blockIdx.x * 256 + threadIdx.x;  // 0..1572863
    const float* src; int8_t* dh; int8_t* dl; int idx; float s256, s;
    if (i < 1048576)      { src = x;  idx = i;           dh = xhi; dl = xlo;
                            s256 = INV_S256; s = INV_S; }
    else if (i < 1310720) { src = Wq; idx = i - 1048576; dh = whi; dl = wlo;
                            s256 = 512.0f; s = 131072.0f; }
    else                  { src = Wk; idx = i - 1310720; dh = whi + 1048576;
                            dl = wlo + 1048576; s256 = 512.0f; s = 131072.0f; }
    float4 v = ((const float4*)src)[idx];
    float vv[4] = {v.x, v.y, v.z, v.w};
    int hp = 0, lp = 0;
#pragma unroll
    for (int c = 0; c < 4; ++c) {
      int h = (int)lrintf(vv[c] * s256);
      h = h > 127 ? 127 : (h < -127 ? -127 : h);
      int l = (int)lrintf(vv[c] * s - 256.0f * (float)h);
      l = l > 127 ? 127 : (l < -127 ? -127 : l);
      hp |= (h & 0xff) << (8 * c);
      lp |= (l & 0xff) << (8 * c);
    }
    ((int*)dh)[idx] = hp;
    ((int*)dl)[idx] = lp;
  } else {
    __shared__ float tile[32][33];
    const int tb = blockIdx.x - 6144;   // 0..4095
    const int bx = tb & 31;             // D/32
    const int by = tb >> 5;             // N/32
    const int tx = threadIdx.x & 31;
    const int ty = threadIdx.x >> 5;    // 0..7
#pragma unroll
    for (int p = 0; p < 4; ++p) {
      const int row = by * 32 + ty + p * 8;
      tile[ty + p * 8][tx] = x[(size_t)row * 1024 + bx * 32 + tx];
    }
    __syncthreads();
#pragma unroll
    for (int p = 0; p < 4; ++p) {
      const int oc = ty + p * 8;  // local col in x == local row in xT
      __half hv = __float2half_rn(tile[tx][oc]);
      xT[(size_t)(bx * 32 + oc) * 4096 + by * 32 + tx] = *(uint16_t*)&hv;
    }
  }
}

extern "C" void kernel_launch(void* const* d_in, const int* in_sizes, int n_in,
                              void* d_out, int out_size, void* d_ws, size_t ws_size,
                              hipStream_t stream) {
  const int N = 4096, D = 1024;
  const float* x  = (const float*)d_in[0];
  const float* Wq = (const float*)d_in[1];
  const float* bq = (const float*)d_in[2];
  const float* Wk = (const float*)d_in[3];
  const float* bk = (const float*)d_in[4];
  float* out = (float*)d_out;

  // workspace layout (MiB offsets)
  char* w = (char*)d_ws;
  const size_t MiB = 1024 * 1024;
  int8_t*    xq_hi  = (int8_t*)   (w + 0  * MiB);  // [N x D]
  int8_t*    xq_lo  = (int8_t*)   (w + 4  * MiB);
  int8_t*    Wqk_hi = (int8_t*)   (w + 8  * MiB);  // [2048 x D]
  int8_t*    Wqk_lo = (int8_t*)   (w + 10 * MiB);
  int8_t*    qk_hi  = (int8_t*)   (w + 12 * MiB);  // [N x 2048]
  int8_t*    qk_lo  = (int8_t*)   (w + 20 * MiB);
  _Float16*  E      = (_Float16*) (w + 36 * MiB);  // [N x N] fp16, 32 MiB
  float2*    stats  = (float2*)   (w + 68 * MiB);  // [N x 32] (m,l), 1 MiB
  uint16_t*  xTh    = (uint16_t*) (w + 72 * MiB);  // [D x N] fp16
  // total 80 MiB

  // 1) fused quantization + transpose-cast  (6144 + 4096 blocks)
  quantT<<<10240, 256, 0, stream>>>(x, Wq, Wk, xq_hi, xq_lo, Wqk_hi, Wqk_lo,
                                    xTh);

  // 2) fused qk projection: i8 16x16x64, 3-phase K-step
  gemm_proj_i8<<<dim3(2048 / 128, N / 128), 256, 0, stream>>>(
      xq_hi, xq_lo, Wqk_hi, Wqk_lo, bq, bk, qk_hi, qk_lo);

  // 3) S = q k^T + tile softmax stats -> E fp16, stats (m_t, l_t)
  gemm_s_stats<<<dim3(N / 128, N / 128), 256, 0, stream>>>(
      qk_hi, qk_lo, qk_hi + 1024, qk_lo + 1024, E, stats);

  // 4) out = sum_t beta_t (E_t x): 512 blocks, 128x64 tiles, no split-K
  gemm_av<<<512, 256, 0, stream>>>((const uint16_t*)E, xTh, stats, out);

  (void)in_sizes; (void)n_in; (void)out_size; (void)ws_size;
}